// Round 8
// baseline (1120.985 us; speedup 1.0000x reference)
//
#include <hip/hip_runtime.h>
#include <math.h>

// Problem constants
#define NTOT   8192
#define BGR    128
#define NPER   64
#define EDIR   65536
#define EKEEP  32768
#define EPSC   1e-5f

typedef unsigned short ushortT;
typedef __attribute__((ext_vector_type(8))) short bf16x8;
typedef __attribute__((ext_vector_type(4))) float f32x4;

// Operand dtype codes: 0 = bf16, 1 = f32, 2 = runtime (read *flagp)
#define C_BF 0
#define C_F32 1
#define C_RT 2

// ---------------- dtype helpers ----------------
__device__ __forceinline__ float bf2f(ushortT u) {
    union { unsigned int i; float f; } v; v.i = ((unsigned int)u) << 16; return v.f;
}
__device__ __forceinline__ ushortT f2bf(float f) {
    unsigned int u = __float_as_uint(f);
    u += 0x7FFFu + ((u >> 16) & 1u);   // round to nearest even
    return (ushortT)(u >> 16);
}
__device__ __forceinline__ float get1(const void* p, long i, int f) {
    return f ? ((const float*)p)[i] : bf2f(((const ushortT*)p)[i]);
}
__device__ __forceinline__ float4 get4(const void* p, long i, int f) {
    if (f) return *(const float4*)((const float*)p + i);
    ushort4 u = *(const ushort4*)((const ushortT*)p + i);
    return make_float4(bf2f(u.x), bf2f(u.y), bf2f(u.z), bf2f(u.w));
}
__device__ __forceinline__ float ld1c(const float* p)   { return *p; }
__device__ __forceinline__ float ld1c(const ushortT* p) { return bf2f(*p); }
__device__ __forceinline__ void st1c(float* p, float v)   { *p = v; }
__device__ __forceinline__ void st1c(ushortT* p, float v) { *p = f2bf(v); }
__device__ __forceinline__ int clampi(int v, int lo, int hi) {
    return v < lo ? lo : (v > hi ? hi : v);
}

// direct global->LDS DMA, 16B per lane (lane-linear LDS destination required)
__device__ __forceinline__ void gld16(const void* g, void* l) {
    __builtin_amdgcn_global_load_lds(
        (const __attribute__((address_space(1))) unsigned int*)g,
        (__attribute__((address_space(3))) unsigned int*)l, 16, 0, 0);
}

// Bijective XCD-chunked block-id swizzle (m204).
__device__ __forceinline__ int xcd_swz(int flat, int nwg) {
    const int q = nwg >> 3, r = nwg & 7;
    const int xcd = flat & 7, idx = flat >> 3;
    return (xcd < r ? xcd * (q + 1) : r * (q + 1) + (xcd - r) * q) + idx;
}

// ---------------------------------------------------------------------------
// Float-input dtype detector (validated R7-R9).
// ---------------------------------------------------------------------------
__launch_bounds__(256)
__global__ void detect_k(const unsigned int* __restrict__ xw, int* __restrict__ flag)
{
    __shared__ int red[256];
    const int t = threadIdx.x;
    int hits = 0;
#pragma unroll
    for (int i = 0; i < 4; ++i) {
        const unsigned w = xw[t*4 + i];
        const unsigned eb = (w >> 7) & 0xFF;
        hits += (eb >= 100 && eb <= 150) ? 1 : 0;
    }
    red[t] = hits; __syncthreads();
#pragma unroll
    for (int s = 128; s > 0; s >>= 1) { if (t < s) red[t] += red[t+s]; __syncthreads(); }
    if (t == 0) *flag = (red[0] < 512) ? 1 : 0;
}

// ---------------------------------------------------------------------------
// R8: 256x256 counted-vmcnt multi-phase bf16 GEMM (T3+T4+T5 + R7 swizzle).
// C = alpha*(A @ B^T), A [m][k], B [n][k], bf16 out. 512 threads = 8 waves
// (2M x 4N), per-wave 128x64 output, BK=64, double-buffered 128 KiB LDS.
// Schedule per K-tile kt (4 phases, one half-tile staged per phase):
//   half order: H0=B-lo H1=B-hi H2=A-lo H3=A-hi (2 gld16 each)
//   q=0: vmcnt(2) [H0-H2(kt) landed; H3(kt) may fly]; barrier; stage H0(kt+1);
//        read B-frags(8)+A-lo frags(4); setprio(1); 16 MFMA; setprio(0)
//   q=1: barrier; stage H1(kt+1); read A-lo(4); 16 MFMA
//   q=2: vmcnt(4) [H3(kt) landed]; barrier; stage H2(kt+1); read A-hi(4); MFMA
//   q=3: barrier; stage H3(kt+1); read A-hi(4); MFMA
// Loads stay in flight across barriers (never vmcnt(0) in the main loop).
// Hazards: check-then-barrier makes per-wave vmcnt globally sufficient;
// buf[nxt] writes never race reads (last reads precede >=1 barrier).
// Final K-tile runs drained (vmcnt(0), no staging) - uniform control flow.
// Requires M%256==0, N%256==0, K%64==0, lda/ldb%8==0.
// ---------------------------------------------------------------------------
__launch_bounds__(512, 2)
__global__ void bgemm256_k(const ushortT* __restrict__ A, const ushortT* __restrict__ B,
                           ushortT* __restrict__ C,
                           int K, int lda, int ldb, int ldc,
                           long sA, long sB, long sC, float alpha)
{
    const int t = threadIdx.x;
    const int lane = t & 63;
    const int l15 = lane & 15, quad = lane >> 4;
    const int wave = t >> 6;
    const int wm = wave >> 2, wn = wave & 3;

    const int gx = gridDim.x, gy = gridDim.y;
    const int nwg = gx * gy * (int)gridDim.z;
    const int flat = xcd_swz(blockIdx.x + gx * (blockIdx.y + gy * blockIdx.z), nwg);
    const int bx = flat % gx;
    const int by = (flat / gx) % gy;
    const int bz = flat / (gx * gy);

    const int m0 = by * 256, n0 = bx * 256;
    const long z = bz;

    __shared__ __align__(16) ushortT As[2][256][64];
    __shared__ __align__(16) ushortT Bs[2][256][64];

    f32x4 acc[8][4] = {};

    // staging: 512 lanes x 16B = 64 rows x 128B per issue; 2 issues per half.
    // XOR swizzle (R7-proven): LDS slot s at row r holds global col-slot s^(r&7).
    const int srow = t >> 3;                    // 0..63
    const int sslot = t & 7;
    const int scol = (sslot ^ (srow & 7)) * 8;  // pre-swizzled source col
    const ushortT* pA = A + z*sA + (long)(m0 + srow) * lda + scol;
    const ushortT* pB = B + z*sB + (long)(n0 + srow) * ldb + scol;

#define STG_B(buf, h, k0) \
    gld16(pB + (long)((h)*128    )*ldb + (k0), &Bs[buf][(h)*128      + srow][sslot*8]); \
    gld16(pB + (long)((h)*128 + 64)*ldb + (k0), &Bs[buf][(h)*128 + 64 + srow][sslot*8]);
#define STG_A(buf, h, k0) \
    gld16(pA + (long)((h)*128    )*lda + (k0), &As[buf][(h)*128      + srow][sslot*8]); \
    gld16(pA + (long)((h)*128 + 64)*lda + (k0), &As[buf][(h)*128 + 64 + srow][sslot*8]);

    // prologue: full K-tile 0 in issue order H0,H1,H2,H3 (8 loads)
    STG_B(0, 0, 0) STG_B(0, 1, 0) STG_A(0, 0, 0) STG_A(0, 1, 0)

    const int NT = K >> 6;
    const int xr = (l15 & 7) * 8;   // read-side XOR
    int cur = 0;

    for (int kt = 0; kt < NT - 1; ++kt) {
        const int k1 = (kt + 1) << 6;
        const int nxt = cur ^ 1;
        bf16x8 bf[4][2];
#pragma unroll
        for (int q = 0; q < 4; ++q) {
            if (q == 0) asm volatile("s_waitcnt vmcnt(2)" ::: "memory");
            if (q == 2) asm volatile("s_waitcnt vmcnt(4)" ::: "memory");
            asm volatile("s_barrier" ::: "memory");
            // stage H_q(kt+1)
            if (q == 0) { STG_B(nxt, 0, k1) }
            else if (q == 1) { STG_B(nxt, 1, k1) }
            else if (q == 2) { STG_A(nxt, 0, k1) }
            else { STG_A(nxt, 1, k1) }
            // ds reads
            if (q == 0) {
#pragma unroll
                for (int nt = 0; nt < 4; ++nt)
#pragma unroll
                    for (int kk = 0; kk < 2; ++kk)
                        bf[nt][kk] = *(const bf16x8*)&Bs[cur][wn*64 + nt*16 + l15][(kk*32 + quad*8) ^ xr];
            }
            bf16x8 af[2][2];
#pragma unroll
            for (int j = 0; j < 2; ++j)
#pragma unroll
                for (int kk = 0; kk < 2; ++kk)
                    af[j][kk] = *(const bf16x8*)&As[cur][wm*128 + (2*q + j)*16 + l15][(kk*32 + quad*8) ^ xr];
            __builtin_amdgcn_s_setprio(1);
#pragma unroll
            for (int j = 0; j < 2; ++j)
#pragma unroll
                for (int nt = 0; nt < 4; ++nt)
#pragma unroll
                    for (int kk = 0; kk < 2; ++kk)
                        acc[2*q + j][nt] = __builtin_amdgcn_mfma_f32_16x16x32_bf16(af[j][kk], bf[nt][kk], acc[2*q + j][nt], 0, 0, 0);
            __builtin_amdgcn_s_setprio(0);
        }
        cur = nxt;
    }

    // final K-tile: drained, no staging
    {
        bf16x8 bf[4][2];
#pragma unroll
        for (int q = 0; q < 4; ++q) {
            if (q == 0) asm volatile("s_waitcnt vmcnt(0)" ::: "memory");
            asm volatile("s_barrier" ::: "memory");
            if (q == 0) {
#pragma unroll
                for (int nt = 0; nt < 4; ++nt)
#pragma unroll
                    for (int kk = 0; kk < 2; ++kk)
                        bf[nt][kk] = *(const bf16x8*)&Bs[cur][wn*64 + nt*16 + l15][(kk*32 + quad*8) ^ xr];
            }
            bf16x8 af[2][2];
#pragma unroll
            for (int j = 0; j < 2; ++j)
#pragma unroll
                for (int kk = 0; kk < 2; ++kk)
                    af[j][kk] = *(const bf16x8*)&As[cur][wm*128 + (2*q + j)*16 + l15][(kk*32 + quad*8) ^ xr];
            __builtin_amdgcn_s_setprio(1);
#pragma unroll
            for (int j = 0; j < 2; ++j)
#pragma unroll
                for (int nt = 0; nt < 4; ++nt)
#pragma unroll
                    for (int kk = 0; kk < 2; ++kk)
                        acc[2*q + j][nt] = __builtin_amdgcn_mfma_f32_16x16x32_bf16(af[j][kk], bf[nt][kk], acc[2*q + j][nt], 0, 0, 0);
            __builtin_amdgcn_s_setprio(0);
        }
    }
#undef STG_A
#undef STG_B

    ushortT* Cb = C + z * sC;
#pragma unroll
    for (int mt = 0; mt < 8; ++mt) {
#pragma unroll
        for (int nt = 0; nt < 4; ++nt) {
            const int col = n0 + wn*64 + nt*16 + l15;
#pragma unroll
            for (int r = 0; r < 4; ++r) {
                const int row = m0 + wm*128 + mt*16 + quad*4 + r;
                Cb[(long)row * ldc + col] = f2bf(alpha * acc[mt][nt][r]);
            }
        }
    }
}

// ---------------------------------------------------------------------------
// Fast bf16 GEMM (R7, validated): C = alpha*(A @ B^T) (+bias f32) (+C).
// B stored [n][k]. 128x128 tile, 4 waves, 16x16x32 MFMA, BK=64, XOR-swizzled
// global_load_lds staging (bank-conflict-free), XCD swizzle.
// Requires M%128==0, N%128==0, K%64==0, lda/ldb%8==0.
// ---------------------------------------------------------------------------
template<class TC, bool BIAS, bool RESID>
__launch_bounds__(256)
__global__ void bgemm_k(const ushortT* __restrict__ A, const ushortT* __restrict__ B,
                        const float* __restrict__ bias, TC* __restrict__ C,
                        int K, int lda, int ldb, int ldc,
                        long sA, long sB, long sC, long biasOff, long bzStride,
                        float alpha)
{
    const int t = threadIdx.x;
    const int lane = t & 63, wave = t >> 6;
    const int l15 = lane & 15, quad = lane >> 4;
    const int wr = (wave >> 1) * 64, wc = (wave & 1) * 64;

    const int gx = gridDim.x, gy = gridDim.y;
    const int nwg = gx * gy * (int)gridDim.z;
    const int flat = xcd_swz(blockIdx.x + gx * (blockIdx.y + gy * blockIdx.z), nwg);
    const int bx = flat % gx;
    const int by = (flat / gx) % gy;
    const int bz = flat / (gx * gy);

    const int m0 = by * 128, n0 = bx * 128;
    const long z = bz;

    __shared__ __align__(16) ushortT As[128][64];
    __shared__ __align__(16) ushortT Bs[128][64];

    f32x4 acc[4][4] = {};

    const int sr = t >> 3;
    const int ssw = ((t & 7) ^ (sr & 7)) * 8;
    const ushortT* pA = A + z*sA + (long)(m0 + sr) * lda + ssw;
    const ushortT* pB = B + z*sB + (long)(n0 + sr) * ldb + ssw;
    ushortT* lA = &As[sr][(t & 7) * 8];
    ushortT* lB = &Bs[sr][(t & 7) * 8];

    for (int k0 = 0; k0 < K; k0 += 64) {
#pragma unroll
        for (int i = 0; i < 4; ++i) {
            gld16(pA + (long)i*32*lda + k0, lA + i*32*64);
            gld16(pB + (long)i*32*ldb + k0, lB + i*32*64);
        }
        __syncthreads();
#pragma unroll
        for (int kh = 0; kh < 2; ++kh) {
            const int ca = (kh*32 + quad*8) ^ ((l15 & 7) * 8);
            bf16x8 af[4], bfr[4];
#pragma unroll
            for (int i = 0; i < 4; ++i) {
                af[i]  = *(const bf16x8*)&As[wr + i*16 + l15][ca];
                bfr[i] = *(const bf16x8*)&Bs[wc + i*16 + l15][ca];
            }
#pragma unroll
            for (int mt = 0; mt < 4; ++mt)
#pragma unroll
                for (int nt = 0; nt < 4; ++nt)
                    acc[mt][nt] = __builtin_amdgcn_mfma_f32_16x16x32_bf16(af[mt], bfr[nt], acc[mt][nt], 0, 0, 0);
        }
        __syncthreads();
    }

    TC* Cb = C + z * sC;
#pragma unroll
    for (int nt = 0; nt < 4; ++nt) {
        const int col = n0 + wc + nt*16 + l15;
        const float bv = BIAS ? bias[biasOff + z*bzStride + col] : 0.f;
#pragma unroll
        for (int mt = 0; mt < 4; ++mt) {
#pragma unroll
            for (int r = 0; r < 4; ++r) {
                const int row = m0 + wr + mt*16 + quad*4 + r;
                TC* cp = Cb + (long)row * ldc + col;
                float val = alpha * acc[mt][nt][r] + bv;
                if constexpr (RESID) val += ld1c(cp);
                st1c(cp, val);
            }
        }
    }
}

// ---------------------------------------------------------------------------
// Generic MFMA GEMM (validated): 64x64 tile, handles RT dtypes, BT, bias,
// relu, resid, transposed store. XCD swizzle. (Only gconv2 gemms use it now.)
// ---------------------------------------------------------------------------
template<class TC, bool BT, bool BIAS, bool RELU, bool RESID, bool CT>
__launch_bounds__(256)
__global__ void gemm_k(const void* __restrict__ A, int cA, long aeOff,
                       const void* __restrict__ B, int cB, long beOff,
                       const void* __restrict__ bias, int cBias, long biasOff, long bzStride,
                       TC* __restrict__ C, const int* __restrict__ flagp,
                       int K, int lda, int ldb, int ldc,
                       long sA, long sB, long sC, float alpha)
{
    const int rtf = *flagp;
    const int fA = (cA == C_RT) ? rtf : cA;
    const int fB = (cB == C_RT) ? rtf : cB;

    const int t = threadIdx.x;
    const int lane = t & 63, wave = t >> 6;
    const int l15 = lane & 15, quad = lane >> 4;

    const int gx = gridDim.x, gy = gridDim.y;
    const int nwg = gx * gy * (int)gridDim.z;
    const int flat = xcd_swz(blockIdx.x + gx * (blockIdx.y + gy * blockIdx.z), nwg);
    const int bx = flat % gx;
    const int by = (flat / gx) % gy;
    const int bz = flat / (gx * gy);

    const int m0 = by * 64, n0 = bx * 64;
    const long z = bz;
    const long aOff = aeOff + z * sA, bOff = beOff + z * sB, cOff = z * sC;

    __shared__ __align__(16) ushortT As[64][40];
    __shared__ __align__(16) ushortT Bs[64][40];

    f32x4 acc[4] = {};

    const int ar = t >> 2, ak = (t & 3) * 8;
    const int bk = t & 31, bn = (t >> 5) * 8;

    for (int k0 = 0; k0 < K; k0 += 32) {
        {
            const long base = aOff + (long)(m0 + ar) * lda + (k0 + ak);
            float4 v0 = get4(A, base, fA);
            float4 v1 = get4(A, base + 4, fA);
            ushortT* dst = &As[ar][ak];
            dst[0]=f2bf(v0.x); dst[1]=f2bf(v0.y); dst[2]=f2bf(v0.z); dst[3]=f2bf(v0.w);
            dst[4]=f2bf(v1.x); dst[5]=f2bf(v1.y); dst[6]=f2bf(v1.z); dst[7]=f2bf(v1.w);
        }
        if constexpr (BT) {
            const long base = bOff + (long)(n0 + ar) * ldb + (k0 + ak);
            float4 v0 = get4(B, base, fB);
            float4 v1 = get4(B, base + 4, fB);
            ushortT* dst = &Bs[ar][ak];
            dst[0]=f2bf(v0.x); dst[1]=f2bf(v0.y); dst[2]=f2bf(v0.z); dst[3]=f2bf(v0.w);
            dst[4]=f2bf(v1.x); dst[5]=f2bf(v1.y); dst[6]=f2bf(v1.z); dst[7]=f2bf(v1.w);
        } else {
            const long base = bOff + (long)(k0 + bk) * ldb + (n0 + bn);
            float4 v0 = get4(B, base, fB);
            float4 v1 = get4(B, base + 4, fB);
            Bs[bn+0][bk] = f2bf(v0.x);
            Bs[bn+1][bk] = f2bf(v0.y);
            Bs[bn+2][bk] = f2bf(v0.z);
            Bs[bn+3][bk] = f2bf(v0.w);
            Bs[bn+4][bk] = f2bf(v1.x);
            Bs[bn+5][bk] = f2bf(v1.y);
            Bs[bn+6][bk] = f2bf(v1.z);
            Bs[bn+7][bk] = f2bf(v1.w);
        }
        __syncthreads();
        const bf16x8 af = *(const bf16x8*)&As[wave*16 + l15][quad*8];
#pragma unroll
        for (int nt = 0; nt < 4; ++nt) {
            const bf16x8 bf = *(const bf16x8*)&Bs[nt*16 + l15][quad*8];
            acc[nt] = __builtin_amdgcn_mfma_f32_16x16x32_bf16(af, bf, acc[nt], 0, 0, 0);
        }
        __syncthreads();
    }

    const int fBias = BIAS ? ((cBias == C_RT) ? rtf : cBias) : 0;
#pragma unroll
    for (int nt = 0; nt < 4; ++nt) {
        const int col = n0 + nt*16 + l15;
        const float bv = BIAS ? get1(bias, biasOff + z*bzStride + col, fBias) : 0.f;
#pragma unroll
        for (int r = 0; r < 4; ++r) {
            const int row = m0 + wave*16 + quad*4 + r;
            TC* cp = CT ? (C + cOff + (long)col * ldc + row)
                        : (C + cOff + (long)row * ldc + col);
            float val = alpha * acc[nt][r] + bv;
            if constexpr (RESID) val += ld1c(cp);
            if constexpr (RELU)  val = fmaxf(val, 0.f);
            st1c(cp, val);
        }
    }
}

// ---------------- block reduction (256 threads) ----------------
__device__ __forceinline__ float blockReduceSum(float v, float* red, int t)
{
    red[t] = v; __syncthreads();
#pragma unroll
    for (int s = 128; s > 0; s >>= 1) {
        if (t < s) red[t] += red[t + s];
        __syncthreads();
    }
    const float r = red[0];
    __syncthreads();
    return r;
}

// ---------------------------------------------------------------------------
// R6: weight convert / transpose-convert to bf16 fast-path layouts.
// ---------------------------------------------------------------------------
__launch_bounds__(256)
__global__ void convbf_k(const void* __restrict__ in, ushortT* __restrict__ out,
                         long n4, const int* __restrict__ flagp)
{
    const int f = *flagp;
    const long i = (long)blockIdx.x*256 + threadIdx.x;
    if (i >= n4) return;
    const long i0 = i * 4;
    if (f) {
        const float4 v = *(const float4*)((const float*)in + i0);
        ushort4 o; o.x=f2bf(v.x); o.y=f2bf(v.y); o.z=f2bf(v.z); o.w=f2bf(v.w);
        *(ushort4*)(out + i0) = o;
    } else {
        *(ushort4*)(out + i0) = *(const ushort4*)((const ushortT*)in + i0);
    }
}

// out[n][k] = in[k][n], 1536x1536, LDS 32x32 tiles
__launch_bounds__(256)
__global__ void tconvbf_k(const void* __restrict__ in, ushortT* __restrict__ out,
                          const int* __restrict__ flagp)
{
    const int f = *flagp;
    __shared__ float tile[32][33];
    const int bx = blockIdx.x, by = blockIdx.y;
    const int tx = threadIdx.x & 31, ty = threadIdx.x >> 5;
#pragma unroll
    for (int i = 0; i < 4; ++i) {
        const int k = by*32 + ty + i*8;
        tile[ty + i*8][tx] = get1(in, (long)k*1536 + bx*32 + tx, f);
    }
    __syncthreads();
#pragma unroll
    for (int i = 0; i < 4; ++i) {
        const int n = bx*32 + ty + i*8;
        out[(long)n*1536 + by*32 + tx] = f2bf(tile[tx][ty + i*8]);
    }
}

// ---------------------------------------------------------------------------
// colcomb split (R2, validated): partials + deterministic reduce.
// ---------------------------------------------------------------------------
__launch_bounds__(256)
__global__ void colcomb_part_k(const void* __restrict__ v, int cv, long voff,
                               const void* __restrict__ W, int cW,
                               float* __restrict__ part, const int* __restrict__ flagp)
{
    const int rtf = *flagp;
    const int fv = (cv == C_RT) ? rtf : cv;
    const int fW = (cW == C_RT) ? rtf : cW;
    const int d = blockIdx.x*256 + threadIdx.x;
    const int c0 = blockIdx.y * 24;
    float a = 0.f;
#pragma unroll
    for (int i = 0; i < 24; ++i) {
        const int c = c0 + i;
        a += get1(v, voff + c, fv) * get1(W, (long)c*1536 + d, fW);
    }
    part[blockIdx.y * 1536 + d] = a;
}

__launch_bounds__(256)
__global__ void colcomb_red_k(const float* __restrict__ part,
                              const void* __restrict__ b, int cb,
                              float* __restrict__ out, const int* __restrict__ flagp)
{
    const int rtf = *flagp;
    const int fb = (cb == C_RT) ? rtf : cb;
    const int d = blockIdx.x*256 + threadIdx.x;
    float a = get1(b, d, fb);
#pragma unroll 8
    for (int cy = 0; cy < 64; ++cy) a += part[cy*1536 + d];
    out[d] = a;
}

// ---------------------------------------------------------------------------
// rowdot: out[r] = scale * sum_c bf2f(W[r*1536+c]) * v[c]   grid 1536 x 256
// ---------------------------------------------------------------------------
__launch_bounds__(256)
__global__ void rowdot_k(const ushortT* __restrict__ W, const float* __restrict__ v,
                         float* __restrict__ out, float scale)
{
    const int r = blockIdx.x, t = threadIdx.x;
    __shared__ float red[256];
    float p = 0.f;
    for (int c = t; c < 1536; c += 256) p += bf2f(W[(long)r*1536 + c]) * v[c];
    const float tot = blockReduceSum(p, red, t);
    if (t == 0) out[r] = scale * tot;
}

// ---------------------------------------------------------------------------
// gconv1 fused (unchanged — validated)
// ---------------------------------------------------------------------------
__launch_bounds__(256)
__global__ void gconv1_k(int b0, const void* __restrict__ x, const int* __restrict__ edges,
                         const void* __restrict__ ea,
                         const void* __restrict__ wembW, const void* __restrict__ wembB,
                         const void* __restrict__ Wrel, const void* __restrict__ brel,
                         const void* __restrict__ Wroot, ushortT* __restrict__ h1,
                         const int* __restrict__ flagp)
{
    const int f = *flagp;
    const int bl = blockIdx.x, g = b0 + bl, t = threadIdx.x;
    __shared__ float s_x[64][5];
    __shared__ float s_agg[64][5];
    __shared__ int   s_cnt[64];
    __shared__ int   s_off[65];
    __shared__ int   s_src[512];
    __shared__ float s_w[512];

    if (t < 64) s_cnt[t] = 0;
    if (t < 320) s_x[t/5][t%5] = get1(x, (long)(g*64 + t/5)*5 + (t%5), f);
    __syncthreads();

    const float w0 = get1(wembW,0,f), w1 = get1(wembW,1,f), w2 = get1(wembW,2,f);
    const float wb = get1(wembB,0,f);
    int sl[2], dl[2], slot[2]; float wv[2];
#pragma unroll
    for (int e2 = 0; e2 < 2; ++e2) {
        const int e = g*512 + t + 256*e2;
        const int s = edges[e], d = edges[EDIR + e];
        sl[e2] = clampi(s - g*64, 0, 63); dl[e2] = clampi(d - g*64, 0, 63);
        const float a0 = get1(ea, 2L*e, f), a1 = get1(ea, 2L*e+1, f);
        wv[e2] = fmaxf(a0*w0 + ((a1 < 0.5f) ? w1 : w2) + wb, 0.f);
        slot[e2] = atomicAdd(&s_cnt[dl[e2]], 1);
    }
    __syncthreads();
    if (t == 0) {
        int r = 0;
        for (int i = 0; i < 64; ++i) { s_off[i] = r; r += s_cnt[i]; }
        s_off[64] = r;
    }
    __syncthreads();
#pragma unroll
    for (int e2 = 0; e2 < 2; ++e2) {
        const int p = s_off[dl[e2]] + slot[e2];
        s_src[p] = sl[e2]; s_w[p] = wv[e2];
    }
    __syncthreads();
    if (t < 320) {
        const int n = t/5, k = t%5;
        float acc = 0.f;
        for (int i = s_off[n]; i < s_off[n+1]; ++i) acc += s_w[i] * s_x[s_src[i]][k];
        s_agg[n][k] = acc;
    }
    __syncthreads();
    float wr[5], wo[5];
#pragma unroll
    for (int k = 0; k < 5; ++k) { wr[k] = get1(Wrel, k*256 + t, f); wo[k] = get1(Wroot, k*256 + t, f); }
    const float bb = get1(brel, t, f);
    for (int n = 0; n < 64; ++n) {
        float v = bb;
#pragma unroll
        for (int k = 0; k < 5; ++k) v += s_agg[n][k]*wr[k] + s_x[n][k]*wo[k];
        h1[(bl*64 + n)*256 + t] = f2bf(fmaxf(v, 0.f));
    }
}

// ---------------------------------------------------------------------------
// gconv2 aggregation (unchanged — validated)
// ---------------------------------------------------------------------------
__launch_bounds__(256)
__global__ void gconv2_agg_k(int b0, const ushortT* __restrict__ h1, const int* __restrict__ edges,
                             const void* __restrict__ ea,
                             const void* __restrict__ wembW, const void* __restrict__ wembB,
                             ushortT* __restrict__ agg2, const int* __restrict__ flagp)
{
    const int f = *flagp;
    const int bl = blockIdx.x, g = b0 + bl, t = threadIdx.x;
    __shared__ int   s_cnt[64];
    __shared__ int   s_off[65];
    __shared__ int   s_src[512];
    __shared__ float s_w[512];

    if (t < 64) s_cnt[t] = 0;
    __syncthreads();

    const float w0 = get1(wembW,0,f), w1 = get1(wembW,1,f), w2 = get1(wembW,2,f);
    const float wb = get1(wembB,0,f);
    int sl[2], dl[2], slot[2]; float wv[2];
#pragma unroll
    for (int e2 = 0; e2 < 2; ++e2) {
        const int e = g*512 + t + 256*e2;
        const int s = edges[e], d = edges[EDIR + e];
        sl[e2] = clampi(s - g*64, 0, 63); dl[e2] = clampi(d - g*64, 0, 63);
        const float a0 = get1(ea, 2L*e, f), a1 = get1(ea, 2L*e+1, f);
        wv[e2] = fmaxf(a0*w0 + ((a1 < 0.5f) ? w1 : w2) + wb, 0.f);
        slot[e2] = atomicAdd(&s_cnt[dl[e2]], 1);
    }
    __syncthreads();
    if (t == 0) {
        int r = 0;
        for (int i = 0; i < 64; ++i) { s_off[i] = r; r += s_cnt[i]; }
        s_off[64] = r;
    }
    __syncthreads();
#pragma unroll
    for (int e2 = 0; e2 < 2; ++e2) {
        const int p = s_off[dl[e2]] + slot[e2];
        s_src[p] = sl[e2]; s_w[p] = wv[e2];
    }
    __syncthreads();
    for (int n = 0; n < 64; ++n) {
        float acc = 0.f;
        const int i0 = s_off[n], i1 = s_off[n+1];
        for (int i = i0; i < i1; ++i)
            acc += s_w[i] * bf2f(h1[(bl*64 + s_src[i])*256 + t]);
        agg2[(bl*64 + n)*256 + t] = f2bf(acc);
    }
}

// ---------------------------------------------------------------------------
// GraphNorm (R7: split the two 256-col halves across blockIdx.y)
// ---------------------------------------------------------------------------
__launch_bounds__(256)
__global__ void gnorm_k(ushortT* __restrict__ h, const void* __restrict__ gw,
                        const void* __restrict__ gb, const void* __restrict__ gms,
                        const int* __restrict__ flagp)
{
    const int f0 = *flagp;
    const int bl = blockIdx.x, t = threadIdx.x;
    const int f = t + 256*blockIdx.y;
    float acc = 0.f;
    for (int n = 0; n < 64; ++n) acc += bf2f(h[(bl*64+n)*512 + f]);
    const float m2 = get1(gms, f, f0) * (acc * (1.f/64.f));
    float v = 0.f;
    for (int n = 0; n < 64; ++n) { const float d = bf2f(h[(bl*64+n)*512 + f]) - m2; v += d*d; }
    const float rs = rsqrtf(v*(1.f/64.f) + EPSC);
    const float g = get1(gw, f, f0), bb = get1(gb, f, f0);
    for (int n = 0; n < 64; ++n) {
        const int idx = (bl*64+n)*512 + f;
        h[idx] = f2bf(g * (bf2f(h[idx]) - m2) * rs + bb);
    }
}

// ---------------------------------------------------------------------------
// SplitSyndromes sort (unchanged — validated)
// ---------------------------------------------------------------------------
__launch_bounds__(256)
__global__ void sort_k(const int* __restrict__ edges, int* __restrict__ sorted_orig,
                       int* __restrict__ se, int* __restrict__ te)
{
    const int b = blockIdx.x, t = threadIdx.x;
    __shared__ int s_keep[512];
    __shared__ int s_key[512];
    __shared__ int s_ckey[256];
    __shared__ int s_corig[256];
#pragma unroll
    for (int e2 = 0; e2 < 2; ++e2) {
        const int el = t + 256*e2;
        const int e = b*512 + el;
        const int s = edges[e], d = edges[EDIR + e];
        s_keep[el] = (s > d) ? 1 : 0;
        s_key[el]  = ((s - b*64) << 6) | (d - b*64);
    }
    __syncthreads();
#pragma unroll
    for (int e2 = 0; e2 < 2; ++e2) {
        const int el = t + 256*e2;
        if (s_keep[el]) {
            int pos = 0;
            for (int j = 0; j < el; ++j) pos += s_keep[j];
            s_ckey[pos]  = s_key[el];
            s_corig[pos] = b*512 + el;
        }
    }
    __syncthreads();
    const int ki = s_ckey[t];
    int rank = 0;
    for (int j = 0; j < 256; ++j) {
        const int kj = s_ckey[j];
        rank += (kj < ki || (kj == ki && j < t)) ? 1 : 0;
    }
    const int orig = s_corig[t];
    const int p = b*256 + rank;
    sorted_orig[p] = orig;
    se[p] = edges[orig];
    te[p] = edges[EDIR + orig];
}

// ---------------------------------------------------------------------------
// Build F_c + bvec[ge] = F[e] . kb  (unchanged — validated)
// ---------------------------------------------------------------------------
__launch_bounds__(256)
__global__ void fbuild_k(int b0, int maxn, const ushortT* __restrict__ h,
                         const int* __restrict__ sorted_orig,
                         const int* __restrict__ se, const int* __restrict__ te,
                         const void* __restrict__ ea,
                         const void* __restrict__ eW, const void* __restrict__ eB,
                         const float* __restrict__ kb,
                         ushortT* __restrict__ F, float* __restrict__ bvec,
                         const int* __restrict__ flagp)
{
    const int fl = *flagp;
    const int e = blockIdx.x, t = threadIdx.x;
    __shared__ float red[256];
    const int ge = b0*256 + e;
    const int s = clampi(se[ge] - b0*64, 0, maxn);
    const int d = clampi(te[ge] - b0*64, 0, maxn);
    const int orig = clampi(sorted_orig[ge], 0, EDIR-1);
    const float a0 = get1(ea, 2L*orig, fl), a1 = get1(ea, 2L*orig + 1, fl);
    float partial = 0.f;
#pragma unroll
    for (int c = 0; c < 6; ++c) {
        const int col = c*256 + t;
        float v;
        if (c < 2) {
            v = bf2f(h[(long)s*512 + col]);
        } else if (c < 4) {
            const int ff = col - 512;
            v = fmaxf(a0*get1(eW, ff, fl)
                      + ((a1 < 0.5f) ? get1(eW, 512+ff, fl) : get1(eW, 1024+ff, fl))
                      + get1(eB, ff, fl), 0.f);
        } else {
            v = bf2f(h[(long)d*512 + (col - 1024)]);
        }
        F[(long)e*1536 + col] = f2bf(v);
        partial += v * kb[col];
    }
    const float tot = blockReduceSum(partial, red, t);
    if (t == 0) bvec[ge] = tot;
}

// ---------------------------------------------------------------------------
// row softmax, bf16 P written IN-PLACE into the first half of the row's own
// f32 storage (own-row aliasing, barrier-separated). P layout: lda=512 ushorts.
// ---------------------------------------------------------------------------
__launch_bounds__(256)
__global__ void softmax_ip_k(float* __restrict__ S)
{
    const long row = blockIdx.x;
    const int t = threadIdx.x;
    __shared__ float red[256];
    const float v = S[row*256 + t];
    red[t] = v; __syncthreads();
#pragma unroll
    for (int s = 128; s > 0; s >>= 1) { if (t < s) red[t] = fmaxf(red[t], red[t+s]); __syncthreads(); }
    const float mx = red[0]; __syncthreads();
    const float e = __expf(v - mx);
    red[t] = e; __syncthreads();
#pragma unroll
    for (int s = 128; s > 0; s >>= 1) { if (t < s) red[t] += red[t+s]; __syncthreads(); }
    const float sum = red[0];
    ((ushortT*)S)[row*512 + t] = f2bf(e / sum);
}

// ---------------- fused LayerNorm + head dot (unchanged — validated) --------
__launch_bounds__(256)
__global__ void ln_head_k(int b0, const ushortT* __restrict__ F, const void* __restrict__ lng,
                          const void* __restrict__ lnb, const void* __restrict__ hW,
                          const void* __restrict__ hB, float* __restrict__ gout,
                          const int* __restrict__ flagp)
{
    const int fl = *flagp;
    const int e = blockIdx.x, t = threadIdx.x;
    __shared__ float red[256];
    float xv[6];
    float s = 0.f;
#pragma unroll
    for (int c = 0; c < 6; ++c) { xv[c] = bf2f(F[(long)e*1536 + c*256 + t]); s += xv[c]; }
    const float tot = blockReduceSum(s, red, t);
    const float mu = tot * (1.f/1536.f);
    float ss = 0.f;
#pragma unroll
    for (int c = 0; c < 6; ++c) { const float d = xv[c] - mu; ss += d*d; }
    const float tot2 = blockReduceSum(ss, red, t);
    const float rs = rsqrtf(tot2 * (1.f/1536.f) + EPSC);
    float p = 0.f;
#pragma unroll
    for (int c = 0; c < 6; ++c) {
        const int col = c*256 + t;
        p += (get1(lng, col, fl) * (xv[c] - mu) * rs + get1(lnb, col, fl)) * get1(hW, col, fl);
    }
    const float tot3 = blockReduceSum(p, red, t);
    if (t == 0) gout[b0*256 + e] = tot3 + get1(hB, 0, fl);
}

// ---------------- final output assembly (unchanged — validated) -------------
__launch_bounds__(128)
__global__ void final_k(const float* __restrict__ gout, const int* __restrict__ se,
                        const int* __restrict__ te, const int* __restrict__ sorted_orig,
                        const void* __restrict__ ea, float* __restrict__ out,
                        const int* __restrict__ flagp)
{
    const int fl = *flagp;
    const int b = blockIdx.x, j = threadIdx.x;
    const int e0 = b*256 + 2*j, e1 = e0 + 1;
    const float p0 = gout[e0], p1 = gout[e1];
    const int idx = (p1 < p0) ? 1 : 0;
    const float val = idx ? p1 : p0;
    const int eo = idx ? e1 : e0;
    const int orig = clampi(sorted_orig[eo], 0, EDIR-1);
    const float cls = get1(ea, 2L*orig + 1, fl);
    out[(b*128 + j)*2 + 0] = (float)se[e0];
    out[(b*128 + j)*2 + 1] = (float)te[e0];
    out[32768 + b*128 + j] = val;
    out[32768 + 16384 + b*128 + j] = cls;
}

// ---------------------------------------------------------------------------
// Launch. R8: the two big GEMMs (T = F@Mp^T and V'^T = Wvo@F^T) move to the
// 256^2 counted-vmcnt multi-phase kernel; everything else unchanged from R7.
// ---------------------------------------------------------------------------
extern "C" void kernel_launch(void* const* d_in, const int* in_sizes, int n_in,
                              void* d_out, int out_size, void* d_ws, size_t ws_size,
                              hipStream_t stream)
{
    (void)out_size;

    const void* x     = d_in[0];
    const int*  edges = (const int*)d_in[1];
    const void* ea    = d_in[2];

    int ws0 = 3;
    while (ws0 < n_in && in_sizes[ws0] != 3) ++ws0;
    if (ws0 + 27 > n_in) ws0 = 5;

    const void* wembW  = d_in[ws0 + 0];
    const void* wembB  = d_in[ws0 + 1];
    const void* g1Wrel = d_in[ws0 + 2];
    const void* g1brel = d_in[ws0 + 3];
    const void* g1Wroot= d_in[ws0 + 4];
    const void* g2Wrel = d_in[ws0 + 5];
    const void* g2brel = d_in[ws0 + 6];
    const void* g2Wroot= d_in[ws0 + 7];
    const void* gnw    = d_in[ws0 + 8];
    const void* gnb    = d_in[ws0 + 9];
    const void* gnms   = d_in[ws0 + 10];
    const void* eembW  = d_in[ws0 + 11];
    const void* eembB  = d_in[ws0 + 12];
    const void* qkvW   = d_in[ws0 + 13];
    const void* qkvb   = d_in[ws0 + 14];
    const void* inWq   = d_in[ws0 + 15];
    const void* inWk   = d_in[ws0 + 16];
    const void* inWv   = d_in[ws0 + 17];
    const void* inbq   = d_in[ws0 + 18];
    // inbk (ws0+19): row-constant score terms -> drop in softmax
    const void* inbv   = d_in[ws0 + 20];
    const void* outW   = d_in[ws0 + 21];
    const void* outb   = d_in[ws0 + 22];
    const void* lng    = d_in[ws0 + 23];
    const void* lnb    = d_in[ws0 + 24];
    const void* headW  = d_in[ws0 + 25];
    const void* headb  = d_in[ws0 + 26];

    char* ws = (char*)d_ws;
    size_t off = 0;
    auto alloc = [&](size_t bytes) {
        void* p = ws + off;
        off = (off + bytes + 255) & ~(size_t)255;
        return p;
    };
    // ---- fixed region (~11 MB) ----
    int*     dflag  = (int*)    alloc(256);
    float*   gout   = (float*)  alloc(EKEEP*4);
    int*     sorted = (int*)    alloc(EKEEP*4);
    int*     seg    = (int*)    alloc(EKEEP*4);
    int*     teg    = (int*)    alloc(EKEEP*4);
    float*   bvec   = (float*)  alloc(EKEEP*4);
    float*   bqc    = (float*)  alloc(1536*4);
    float*   bvc    = (float*)  alloc(1536*4);
    float*   kb     = (float*)  alloc(1536*4);
    float*   bvo    = (float*)  alloc(1536*4);
    float*   colpart= (float*)  alloc(64L*1536*4);
    ushortT* MpWv   = (ushortT*)alloc(2L*1536*1536*2); // [Mp^T ; Wvo] contiguous
    ushortT* MpT    = MpWv;                            // Mp^T, [n][k]
    ushortT* Wvo    = MpWv + 1536L*1536;               // Wvo, ROW-major [m][k]
    const size_t fixedB = off;

    // ---- union region (phase-W scratch; overlaps chunk scratch) ----
    // layout: [Wqc][Wkc][Wvc][outWT][qkvWbf(3)][inWqT][inWkT][inWvT]
    const long W2 = 1536L * 1536;
    ushortT* Wqc    = (ushortT*)(ws + fixedB);
    ushortT* Wkc    = Wqc + W2;
    ushortT* Wvc    = Wqc + 2*W2;
    ushortT* outWT  = Wqc + 3*W2;
    ushortT* qkvWbf = Wqc + 4*W2;     // 1536x4608
    ushortT* inWqT  = Wqc + 7*W2;
    ushortT* inWkT  = Wqc + 8*W2;     // adjacent (z=3 B stride = W2)
    ushortT* inWvT  = Wqc + 9*W2;

    // ---- chunk scratch (G=128 guaranteed: perG = 1.97 MB -> 263 MB total) --
    const size_t perG = 64L*512*2 + 2L*64*256*2 + 2L*256*1536*2 + 256L*256*4;
    int G = 128;
    while (G > 1 && fixedB + (size_t)G*perG + 65536 > ws_size) G >>= 1;

    size_t coff = fixedB;
    auto calloc2 = [&](size_t bytes) {
        void* p = ws + coff;
        coff = (coff + bytes + 255) & ~(size_t)255;
        return p;
    };
    ushortT* h_c  = (ushortT*)calloc2((size_t)G*64*512*2);
    ushortT* h1_c = (ushortT*)calloc2((size_t)G*64*256*2);
    ushortT* ag_c = (ushortT*)calloc2((size_t)G*64*256*2);
    ushortT* F_c  = (ushortT*)calloc2((size_t)G*256*1536*2);
    ushortT* T_c  = (ushortT*)calloc2((size_t)G*256*1536*2);  // T, then V'^T
    float*   S_c  = (float*)  calloc2((size_t)G*256*256*4);

    const float scale = 0.02551551815399144f;  // 1/sqrt(1536)
    const dim3 blk(256);

    detect_k<<<1, blk, 0, stream>>>((const unsigned int*)x, dflag);
    sort_k<<<128, blk, 0, stream>>>(edges, sorted, seg, teg);

    // ---- phase W ----
    convbf_k<<<(1536*4608/4 + 255)/256, blk, 0, stream>>>(qkvW, qkvWbf, 1536L*4608/4, dflag);
    tconvbf_k<<<dim3(48,48), blk, 0, stream>>>(inWq, inWqT, dflag);
    tconvbf_k<<<dim3(48,48), blk, 0, stream>>>(inWk, inWkT, dflag);
    tconvbf_k<<<dim3(48,48), blk, 0, stream>>>(inWv, inWvT, dflag);
    tconvbf_k<<<dim3(48,48), blk, 0, stream>>>(outW, outWT, dflag);
    // (Wqc,Wkc,Wvc) z=3 batch: A = qkvWbf k-slices (sA=1536), B = inW{q,k,v}T
    bgemm_k<ushortT,false,false><<<dim3(12,12,3), blk, 0, stream>>>(
        qkvWbf, inWqT, nullptr, Wqc, 1536, 4608, 1536, 1536,
        1536L, W2, W2, 0, 0, 1.f);
    colcomb_part_k<<<dim3(6,64), blk, 0, stream>>>(qkvb, C_RT, 0, inWq, C_RT, colpart, dflag);
    colcomb_red_k<<<6, blk, 0, stream>>>(colpart, inbq, C_RT, bqc, dflag);
    // kb = scale * Wkc @ bqc
    rowdot_k<<<1536, blk, 0, stream>>>(Wkc, bqc, kb, scale);
    colcomb_part_k<<<dim3(6,64), blk, 0, stream>>>(qkvb, C_RT, 3072, inWv, C_RT, colpart, dflag);
    colcomb_red_k<<<6, blk, 0, stream>>>(colpart, inbv, C_RT, bvc, dflag);
    // (MpT, Wvo) z=2 batch, unscaled (scale lives in the S-gemm alpha):
    //   z=0: MpT = Wkc @ Wqc^T
    //   z=1: Wvo = Wvc @ outWT^T = Wvc @ outW   (row-major Wvo)
    bgemm_k<ushortT,false,false><<<dim3(12,12,2), blk, 0, stream>>>(
        Wkc, Wqc, nullptr, MpT, 1536, 1536, 1536, 1536,
        W2, 3*W2, W2, 0, 0, 1.f);
    colcomb_part_k<<<dim3(6,64), blk, 0, stream>>>(bvc, C_F32, 0, outW, C_RT, colpart, dflag);
    colcomb_red_k<<<6, blk, 0, stream>>>(colpart, outb, C_RT, bvo, dflag);

    // ---- per-chunk pipeline ----
    const int nchunk = 128 / G;
    const int EC = G * 256;
    for (int c = 0; c < nchunk; ++c) {
        const int b0 = c * G;
        const int maxn = G*64 - 1;
        gconv1_k<<<G, blk, 0, stream>>>(b0, x, edges, ea, wembW, wembB,
                                        g1Wrel, g1brel, g1Wroot, h1_c, dflag);
        gconv2_agg_k<<<G, blk, 0, stream>>>(b0, h1_c, edges, ea, wembW, wembB, ag_c, dflag);
        gemm_k<ushortT,false,true,false,false,false><<<dim3(8,G,1), blk, 0, stream>>>(
            ag_c, C_BF, 0, g2Wrel, C_RT, 0, g2brel, C_RT, 0, 0, h_c, dflag,
            256, 256, 512, 512, 0,0,0, 1.f);
        gemm_k<ushortT,false,false,true,true,false><<<dim3(8,G,1), blk, 0, stream>>>(
            h1_c, C_BF, 0, g2Wroot, C_RT, 0, (const void*)nullptr, C_BF, 0, 0, h_c, dflag,
            256, 256, 512, 512, 0,0,0, 1.f);
        gnorm_k<<<dim3(G,2), blk, 0, stream>>>(h_c, gnw, gnb, gnms, dflag);
        fbuild_k<<<EC, blk, 0, stream>>>(b0, maxn, h_c, sorted, seg, teg, ea,
                                         eembW, eembB, kb, F_c, bvec, dflag);
        // T = F @ Mp^T   (256^2 counted-vmcnt kernel)
        bgemm256_k<<<dim3(6, EC/256, 1), dim3(512), 0, stream>>>(
            F_c, MpT, T_c, 1536, 1536, 1536, 1536, 0, 0, 0, 1.f);
        // S = scale * T@F^T + bvec
        bgemm_k<float,true,false><<<dim3(2, 2, G), blk, 0, stream>>>(
            T_c, F_c, bvec + (long)b0*256, S_c, 1536, 1536, 1536, 256,
            256L*1536, 256L*1536, 65536L, 0, 256, scale);
        softmax_ip_k<<<EC, blk, 0, stream>>>(S_c);
        // V'^T_b = Wvo @ F_b^T   (into T_c; T dead after S-gemm)
        bgemm256_k<<<dim3(1, 6, G), dim3(512), 0, stream>>>(
            Wvo, F_c, T_c, 1536, 1536, 1536, 256,
            0L, 256L*1536, 256L*1536, 1.f);
        // F_b += P_b @ V'_b + bvo   (A = bf16 P in S_c, lda=512 ushorts)
        bgemm_k<ushortT,true,true><<<dim3(12, 2, G), blk, 0, stream>>>(
            (const ushortT*)S_c, T_c, bvo, F_c, 256, 512, 256, 1536,
            131072L, 256L*1536, 256L*1536, 0, 0, 1.f);
        ln_head_k<<<EC, blk, 0, stream>>>(b0, F_c, lng, lnb, headW, headb, gout, dflag);
    }

    final_k<<<128, dim3(128), 0, stream>>>(gout, seg, teg, sorted, ea, (float*)d_out, dflag);
}

// Round 9
// 1025.255 us; speedup vs baseline: 1.0934x; 1.0934x over previous
//
#include <hip/hip_runtime.h>
#include <math.h>

// Problem constants
#define NTOT   8192
#define BGR    128
#define NPER   64
#define EDIR   65536
#define EKEEP  32768
#define EPSC   1e-5f

typedef unsigned short ushortT;
typedef __attribute__((ext_vector_type(8))) short bf16x8;
typedef __attribute__((ext_vector_type(4))) float f32x4;

// Operand dtype codes: 0 = bf16, 1 = f32, 2 = runtime (read *flagp)
#define C_BF 0
#define C_F32 1
#define C_RT 2

// ---------------- dtype helpers ----------------
__device__ __forceinline__ float bf2f(ushortT u) {
    union { unsigned int i; float f; } v; v.i = ((unsigned int)u) << 16; return v.f;
}
__device__ __forceinline__ ushortT f2bf(float f) {
    unsigned int u = __float_as_uint(f);
    u += 0x7FFFu + ((u >> 16) & 1u);   // round to nearest even
    return (ushortT)(u >> 16);
}
__device__ __forceinline__ float get1(const void* p, long i, int f) {
    return f ? ((const float*)p)[i] : bf2f(((const ushortT*)p)[i]);
}
__device__ __forceinline__ float ld1c(const float* p)   { return *p; }
__device__ __forceinline__ float ld1c(const ushortT* p) { return bf2f(*p); }
__device__ __forceinline__ void st1c(float* p, float v)   { *p = v; }
__device__ __forceinline__ void st1c(ushortT* p, float v) { *p = f2bf(v); }
__device__ __forceinline__ int clampi(int v, int lo, int hi) {
    return v < lo ? lo : (v > hi ? hi : v);
}

// direct global->LDS DMA, 16B per lane (lane-linear LDS destination required)
__device__ __forceinline__ void gld16(const void* g, void* l) {
    __builtin_amdgcn_global_load_lds(
        (const __attribute__((address_space(1))) unsigned int*)g,
        (__attribute__((address_space(3))) unsigned int*)l, 16, 0, 0);
}

// Bijective XCD-chunked block-id swizzle (m204).
__device__ __forceinline__ int xcd_swz(int flat, int nwg) {
    const int q = nwg >> 3, r = nwg & 7;
    const int xcd = flat & 7, idx = flat >> 3;
    return (xcd < r ? xcd * (q + 1) : r * (q + 1) + (xcd - r) * q) + idx;
}

// ---------------------------------------------------------------------------
// Float-input dtype detector (validated R7-R9).
// ---------------------------------------------------------------------------
__launch_bounds__(256)
__global__ void detect_k(const unsigned int* __restrict__ xw, int* __restrict__ flag)
{
    __shared__ int red[256];
    const int t = threadIdx.x;
    int hits = 0;
#pragma unroll
    for (int i = 0; i < 4; ++i) {
        const unsigned w = xw[t*4 + i];
        const unsigned eb = (w >> 7) & 0xFF;
        hits += (eb >= 100 && eb <= 150) ? 1 : 0;
    }
    red[t] = hits; __syncthreads();
#pragma unroll
    for (int s = 128; s > 0; s >>= 1) { if (t < s) red[t] += red[t+s]; __syncthreads(); }
    if (t == 0) *flag = (red[0] < 512) ? 1 : 0;
}

// ---------------------------------------------------------------------------
// Fast bf16 GEMM (R7, validated; R9 adds RELU flag):
// C = alpha*(A @ B^T) (+bias f32) (+C) (relu?). B stored [n][k]. 128x128
// tile, 4 waves, 16x16x32 MFMA, BK=64, XOR-swizzled global_load_lds staging
// (bank-conflict-free: SQ_LDS_BANK_CONFLICT==0 measured), XCD swizzle.
// [R8 NOTE: a 256^2 counted-vmcnt variant regressed to 709 TF vs this
//  kernel's 843 TF — phase/half wait-ledger mismatch; reverted.]
// Requires M%128==0, N%128==0, K%64==0, lda/ldb%8==0.
// ---------------------------------------------------------------------------
template<class TC, bool BIAS, bool RESID, bool RELU>
__launch_bounds__(256)
__global__ void bgemm_k(const ushortT* __restrict__ A, const ushortT* __restrict__ B,
                        const float* __restrict__ bias, TC* __restrict__ C,
                        int K, int lda, int ldb, int ldc,
                        long sA, long sB, long sC, long biasOff, long bzStride,
                        float alpha)
{
    const int t = threadIdx.x;
    const int lane = t & 63, wave = t >> 6;
    const int l15 = lane & 15, quad = lane >> 4;
    const int wr = (wave >> 1) * 64, wc = (wave & 1) * 64;

    const int gx = gridDim.x, gy = gridDim.y;
    const int nwg = gx * gy * (int)gridDim.z;
    const int flat = xcd_swz(blockIdx.x + gx * (blockIdx.y + gy * blockIdx.z), nwg);
    const int bx = flat % gx;
    const int by = (flat / gx) % gy;
    const int bz = flat / (gx * gy);

    const int m0 = by * 128, n0 = bx * 128;
    const long z = bz;

    __shared__ __align__(16) ushortT As[128][64];
    __shared__ __align__(16) ushortT Bs[128][64];

    f32x4 acc[4][4] = {};

    const int sr = t >> 3;
    const int ssw = ((t & 7) ^ (sr & 7)) * 8;
    const ushortT* pA = A + z*sA + (long)(m0 + sr) * lda + ssw;
    const ushortT* pB = B + z*sB + (long)(n0 + sr) * ldb + ssw;
    ushortT* lA = &As[sr][(t & 7) * 8];
    ushortT* lB = &Bs[sr][(t & 7) * 8];

    for (int k0 = 0; k0 < K; k0 += 64) {
#pragma unroll
        for (int i = 0; i < 4; ++i) {
            gld16(pA + (long)i*32*lda + k0, lA + i*32*64);
            gld16(pB + (long)i*32*ldb + k0, lB + i*32*64);
        }
        __syncthreads();
#pragma unroll
        for (int kh = 0; kh < 2; ++kh) {
            const int ca = (kh*32 + quad*8) ^ ((l15 & 7) * 8);
            bf16x8 af[4], bfr[4];
#pragma unroll
            for (int i = 0; i < 4; ++i) {
                af[i]  = *(const bf16x8*)&As[wr + i*16 + l15][ca];
                bfr[i] = *(const bf16x8*)&Bs[wc + i*16 + l15][ca];
            }
#pragma unroll
            for (int mt = 0; mt < 4; ++mt)
#pragma unroll
                for (int nt = 0; nt < 4; ++nt)
                    acc[mt][nt] = __builtin_amdgcn_mfma_f32_16x16x32_bf16(af[mt], bfr[nt], acc[mt][nt], 0, 0, 0);
        }
        __syncthreads();
    }

    TC* Cb = C + z * sC;
#pragma unroll
    for (int nt = 0; nt < 4; ++nt) {
        const int col = n0 + wc + nt*16 + l15;
        const float bv = BIAS ? bias[biasOff + z*bzStride + col] : 0.f;
#pragma unroll
        for (int mt = 0; mt < 4; ++mt) {
#pragma unroll
            for (int r = 0; r < 4; ++r) {
                const int row = m0 + wr + mt*16 + quad*4 + r;
                TC* cp = Cb + (long)row * ldc + col;
                float val = alpha * acc[mt][nt][r] + bv;
                if constexpr (RESID) val += ld1c(cp);
                if constexpr (RELU)  val = fmaxf(val, 0.f);
                st1c(cp, val);
            }
        }
    }
}

// ---------------- block reduction (256 threads) ----------------
__device__ __forceinline__ float blockReduceSum(float v, float* red, int t)
{
    red[t] = v; __syncthreads();
#pragma unroll
    for (int s = 128; s > 0; s >>= 1) {
        if (t < s) red[t] += red[t + s];
        __syncthreads();
    }
    const float r = red[0];
    __syncthreads();
    return r;
}

// ---------------------------------------------------------------------------
// R6: weight convert / transpose-convert to bf16 fast-path layouts.
// ---------------------------------------------------------------------------
__launch_bounds__(256)
__global__ void convbf_k(const void* __restrict__ in, ushortT* __restrict__ out,
                         long n4, const int* __restrict__ flagp)
{
    const int f = *flagp;
    const long i = (long)blockIdx.x*256 + threadIdx.x;
    if (i >= n4) return;
    const long i0 = i * 4;
    if (f) {
        const float4 v = *(const float4*)((const float*)in + i0);
        ushort4 o; o.x=f2bf(v.x); o.y=f2bf(v.y); o.z=f2bf(v.z); o.w=f2bf(v.w);
        *(ushort4*)(out + i0) = o;
    } else {
        *(ushort4*)(out + i0) = *(const ushort4*)((const ushortT*)in + i0);
    }
}

// out[n][k] = in[k][n], 1536x1536, LDS 32x32 tiles
__launch_bounds__(256)
__global__ void tconvbf_k(const void* __restrict__ in, ushortT* __restrict__ out,
                          const int* __restrict__ flagp)
{
    const int f = *flagp;
    __shared__ float tile[32][33];
    const int bx = blockIdx.x, by = blockIdx.y;
    const int tx = threadIdx.x & 31, ty = threadIdx.x >> 5;
#pragma unroll
    for (int i = 0; i < 4; ++i) {
        const int k = by*32 + ty + i*8;
        tile[ty + i*8][tx] = get1(in, (long)k*1536 + bx*32 + tx, f);
    }
    __syncthreads();
#pragma unroll
    for (int i = 0; i < 4; ++i) {
        const int n = bx*32 + ty + i*8;
        out[(long)n*1536 + by*32 + tx] = f2bf(tile[tx][ty + i*8]);
    }
}

// R9: transpose-convert [256][512] k-major weight into Wg2T[n][512] at column
// offset koff (fused-gconv2 B operand). 32x32 LDS tiles, coalesced both sides.
__launch_bounds__(256)
__global__ void tconv512_k(const void* __restrict__ in, ushortT* __restrict__ out,
                           int koff, const int* __restrict__ flagp)
{
    const int f = *flagp;
    __shared__ float tile[32][33];
    const int bx = blockIdx.x, by = blockIdx.y;   // bx: n-tile (16), by: k-tile (8)
    const int tx = threadIdx.x & 31, ty = threadIdx.x >> 5;
#pragma unroll
    for (int i = 0; i < 4; ++i) {
        const int k = by*32 + ty + i*8;           // 0..255
        tile[ty + i*8][tx] = get1(in, (long)k*512 + bx*32 + tx, f);
    }
    __syncthreads();
#pragma unroll
    for (int i = 0; i < 4; ++i) {
        const int n = bx*32 + ty + i*8;           // 0..511
        out[(long)n*512 + koff + by*32 + tx] = f2bf(tile[tx][ty + i*8]);
    }
}

// R9: small RT->f32 convert (bias vectors)
__launch_bounds__(256)
__global__ void convf32_k(const void* __restrict__ in, float* __restrict__ out,
                          int n, const int* __restrict__ flagp)
{
    const int f = *flagp;
    const int i = blockIdx.x*256 + threadIdx.x;
    if (i < n) out[i] = get1(in, i, f);
}

// ---------------------------------------------------------------------------
// colcomb split (R2, validated): partials + deterministic reduce.
// ---------------------------------------------------------------------------
__launch_bounds__(256)
__global__ void colcomb_part_k(const void* __restrict__ v, int cv, long voff,
                               const void* __restrict__ W, int cW,
                               float* __restrict__ part, const int* __restrict__ flagp)
{
    const int rtf = *flagp;
    const int fv = (cv == C_RT) ? rtf : cv;
    const int fW = (cW == C_RT) ? rtf : cW;
    const int d = blockIdx.x*256 + threadIdx.x;
    const int c0 = blockIdx.y * 24;
    float a = 0.f;
#pragma unroll
    for (int i = 0; i < 24; ++i) {
        const int c = c0 + i;
        a += get1(v, voff + c, fv) * get1(W, (long)c*1536 + d, fW);
    }
    part[blockIdx.y * 1536 + d] = a;
}

__launch_bounds__(256)
__global__ void colcomb_red_k(const float* __restrict__ part,
                              const void* __restrict__ b, int cb,
                              float* __restrict__ out, const int* __restrict__ flagp)
{
    const int rtf = *flagp;
    const int fb = (cb == C_RT) ? rtf : cb;
    const int d = blockIdx.x*256 + threadIdx.x;
    float a = get1(b, d, fb);
#pragma unroll 8
    for (int cy = 0; cy < 64; ++cy) a += part[cy*1536 + d];
    out[d] = a;
}

// ---------------------------------------------------------------------------
// rowdot: out[r] = scale * sum_c bf2f(W[r*1536+c]) * v[c]   grid 1536 x 256
// ---------------------------------------------------------------------------
__launch_bounds__(256)
__global__ void rowdot_k(const ushortT* __restrict__ W, const float* __restrict__ v,
                         float* __restrict__ out, float scale)
{
    const int r = blockIdx.x, t = threadIdx.x;
    __shared__ float red[256];
    float p = 0.f;
    for (int c = t; c < 1536; c += 256) p += bf2f(W[(long)r*1536 + c]) * v[c];
    const float tot = blockReduceSum(p, red, t);
    if (t == 0) out[r] = scale * tot;
}

// ---------------------------------------------------------------------------
// gconv1 fused (validated; R9: h1 written into ah[:,256:512], lda 512)
// ---------------------------------------------------------------------------
__launch_bounds__(256)
__global__ void gconv1_k(int b0, const void* __restrict__ x, const int* __restrict__ edges,
                         const void* __restrict__ ea,
                         const void* __restrict__ wembW, const void* __restrict__ wembB,
                         const void* __restrict__ Wrel, const void* __restrict__ brel,
                         const void* __restrict__ Wroot, ushortT* __restrict__ ah,
                         const int* __restrict__ flagp)
{
    const int f = *flagp;
    const int bl = blockIdx.x, g = b0 + bl, t = threadIdx.x;
    __shared__ float s_x[64][5];
    __shared__ float s_agg[64][5];
    __shared__ int   s_cnt[64];
    __shared__ int   s_off[65];
    __shared__ int   s_src[512];
    __shared__ float s_w[512];

    if (t < 64) s_cnt[t] = 0;
    if (t < 320) s_x[t/5][t%5] = get1(x, (long)(g*64 + t/5)*5 + (t%5), f);
    __syncthreads();

    const float w0 = get1(wembW,0,f), w1 = get1(wembW,1,f), w2 = get1(wembW,2,f);
    const float wb = get1(wembB,0,f);
    int sl[2], dl[2], slot[2]; float wv[2];
#pragma unroll
    for (int e2 = 0; e2 < 2; ++e2) {
        const int e = g*512 + t + 256*e2;
        const int s = edges[e], d = edges[EDIR + e];
        sl[e2] = clampi(s - g*64, 0, 63); dl[e2] = clampi(d - g*64, 0, 63);
        const float a0 = get1(ea, 2L*e, f), a1 = get1(ea, 2L*e+1, f);
        wv[e2] = fmaxf(a0*w0 + ((a1 < 0.5f) ? w1 : w2) + wb, 0.f);
        slot[e2] = atomicAdd(&s_cnt[dl[e2]], 1);
    }
    __syncthreads();
    if (t == 0) {
        int r = 0;
        for (int i = 0; i < 64; ++i) { s_off[i] = r; r += s_cnt[i]; }
        s_off[64] = r;
    }
    __syncthreads();
#pragma unroll
    for (int e2 = 0; e2 < 2; ++e2) {
        const int p = s_off[dl[e2]] + slot[e2];
        s_src[p] = sl[e2]; s_w[p] = wv[e2];
    }
    __syncthreads();
    if (t < 320) {
        const int n = t/5, k = t%5;
        float acc = 0.f;
        for (int i = s_off[n]; i < s_off[n+1]; ++i) acc += s_w[i] * s_x[s_src[i]][k];
        s_agg[n][k] = acc;
    }
    __syncthreads();
    float wr[5], wo[5];
#pragma unroll
    for (int k = 0; k < 5; ++k) { wr[k] = get1(Wrel, k*256 + t, f); wo[k] = get1(Wroot, k*256 + t, f); }
    const float bb = get1(brel, t, f);
    for (int n = 0; n < 64; ++n) {
        float v = bb;
#pragma unroll
        for (int k = 0; k < 5; ++k) v += s_agg[n][k]*wr[k] + s_x[n][k]*wo[k];
        ah[(long)(bl*64 + n)*512 + 256 + t] = f2bf(fmaxf(v, 0.f));
    }
}

// ---------------------------------------------------------------------------
// gconv2 aggregation (validated; R9: reads h1 from ah[:,256:512], writes agg
// into ah[:,0:256] -> one fused K=512 bgemm computes gconv2)
// ---------------------------------------------------------------------------
__launch_bounds__(256)
__global__ void gconv2_agg_k(int b0, ushortT* __restrict__ ah, const int* __restrict__ edges,
                             const void* __restrict__ ea,
                             const void* __restrict__ wembW, const void* __restrict__ wembB,
                             const int* __restrict__ flagp)
{
    const int f = *flagp;
    const int bl = blockIdx.x, g = b0 + bl, t = threadIdx.x;
    __shared__ int   s_cnt[64];
    __shared__ int   s_off[65];
    __shared__ int   s_src[512];
    __shared__ float s_w[512];

    if (t < 64) s_cnt[t] = 0;
    __syncthreads();

    const float w0 = get1(wembW,0,f), w1 = get1(wembW,1,f), w2 = get1(wembW,2,f);
    const float wb = get1(wembB,0,f);
    int sl[2], dl[2], slot[2]; float wv[2];
#pragma unroll
    for (int e2 = 0; e2 < 2; ++e2) {
        const int e = g*512 + t + 256*e2;
        const int s = edges[e], d = edges[EDIR + e];
        sl[e2] = clampi(s - g*64, 0, 63); dl[e2] = clampi(d - g*64, 0, 63);
        const float a0 = get1(ea, 2L*e, f), a1 = get1(ea, 2L*e+1, f);
        wv[e2] = fmaxf(a0*w0 + ((a1 < 0.5f) ? w1 : w2) + wb, 0.f);
        slot[e2] = atomicAdd(&s_cnt[dl[e2]], 1);
    }
    __syncthreads();
    if (t == 0) {
        int r = 0;
        for (int i = 0; i < 64; ++i) { s_off[i] = r; r += s_cnt[i]; }
        s_off[64] = r;
    }
    __syncthreads();
#pragma unroll
    for (int e2 = 0; e2 < 2; ++e2) {
        const int p = s_off[dl[e2]] + slot[e2];
        s_src[p] = sl[e2]; s_w[p] = wv[e2];
    }
    __syncthreads();
    for (int n = 0; n < 64; ++n) {
        float acc = 0.f;
        const int i0 = s_off[n], i1 = s_off[n+1];
        for (int i = i0; i < i1; ++i)
            acc += s_w[i] * bf2f(ah[(long)(bl*64 + s_src[i])*512 + 256 + t]);
        ah[(long)(bl*64 + n)*512 + t] = f2bf(acc);
    }
}

// ---------------------------------------------------------------------------
// GraphNorm (R7: split the two 256-col halves across blockIdx.y)
// ---------------------------------------------------------------------------
__launch_bounds__(256)
__global__ void gnorm_k(ushortT* __restrict__ h, const void* __restrict__ gw,
                        const void* __restrict__ gb, const void* __restrict__ gms,
                        const int* __restrict__ flagp)
{
    const int f0 = *flagp;
    const int bl = blockIdx.x, t = threadIdx.x;
    const int f = t + 256*blockIdx.y;
    float acc = 0.f;
    for (int n = 0; n < 64; ++n) acc += bf2f(h[(bl*64+n)*512 + f]);
    const float m2 = get1(gms, f, f0) * (acc * (1.f/64.f));
    float v = 0.f;
    for (int n = 0; n < 64; ++n) { const float d = bf2f(h[(bl*64+n)*512 + f]) - m2; v += d*d; }
    const float rs = rsqrtf(v*(1.f/64.f) + EPSC);
    const float g = get1(gw, f, f0), bb = get1(gb, f, f0);
    for (int n = 0; n < 64; ++n) {
        const int idx = (bl*64+n)*512 + f;
        h[idx] = f2bf(g * (bf2f(h[idx]) - m2) * rs + bb);
    }
}

// ---------------------------------------------------------------------------
// SplitSyndromes sort (unchanged — validated)
// ---------------------------------------------------------------------------
__launch_bounds__(256)
__global__ void sort_k(const int* __restrict__ edges, int* __restrict__ sorted_orig,
                       int* __restrict__ se, int* __restrict__ te)
{
    const int b = blockIdx.x, t = threadIdx.x;
    __shared__ int s_keep[512];
    __shared__ int s_key[512];
    __shared__ int s_ckey[256];
    __shared__ int s_corig[256];
#pragma unroll
    for (int e2 = 0; e2 < 2; ++e2) {
        const int el = t + 256*e2;
        const int e = b*512 + el;
        const int s = edges[e], d = edges[EDIR + e];
        s_keep[el] = (s > d) ? 1 : 0;
        s_key[el]  = ((s - b*64) << 6) | (d - b*64);
    }
    __syncthreads();
#pragma unroll
    for (int e2 = 0; e2 < 2; ++e2) {
        const int el = t + 256*e2;
        if (s_keep[el]) {
            int pos = 0;
            for (int j = 0; j < el; ++j) pos += s_keep[j];
            s_ckey[pos]  = s_key[el];
            s_corig[pos] = b*512 + el;
        }
    }
    __syncthreads();
    const int ki = s_ckey[t];
    int rank = 0;
    for (int j = 0; j < 256; ++j) {
        const int kj = s_ckey[j];
        rank += (kj < ki || (kj == ki && j < t)) ? 1 : 0;
    }
    const int orig = s_corig[t];
    const int p = b*256 + rank;
    sorted_orig[p] = orig;
    se[p] = edges[orig];
    te[p] = edges[EDIR + orig];
}

// ---------------------------------------------------------------------------
// Build F_c + bvec[ge] = F[e] . kb  (unchanged — validated)
// ---------------------------------------------------------------------------
__launch_bounds__(256)
__global__ void fbuild_k(int b0, int maxn, const ushortT* __restrict__ h,
                         const int* __restrict__ sorted_orig,
                         const int* __restrict__ se, const int* __restrict__ te,
                         const void* __restrict__ ea,
                         const void* __restrict__ eW, const void* __restrict__ eB,
                         const float* __restrict__ kb,
                         ushortT* __restrict__ F, float* __restrict__ bvec,
                         const int* __restrict__ flagp)
{
    const int fl = *flagp;
    const int e = blockIdx.x, t = threadIdx.x;
    __shared__ float red[256];
    const int ge = b0*256 + e;
    const int s = clampi(se[ge] - b0*64, 0, maxn);
    const int d = clampi(te[ge] - b0*64, 0, maxn);
    const int orig = clampi(sorted_orig[ge], 0, EDIR-1);
    const float a0 = get1(ea, 2L*orig, fl), a1 = get1(ea, 2L*orig + 1, fl);
    float partial = 0.f;
#pragma unroll
    for (int c = 0; c < 6; ++c) {
        const int col = c*256 + t;
        float v;
        if (c < 2) {
            v = bf2f(h[(long)s*512 + col]);
        } else if (c < 4) {
            const int ff = col - 512;
            v = fmaxf(a0*get1(eW, ff, fl)
                      + ((a1 < 0.5f) ? get1(eW, 512+ff, fl) : get1(eW, 1024+ff, fl))
                      + get1(eB, ff, fl), 0.f);
        } else {
            v = bf2f(h[(long)d*512 + (col - 1024)]);
        }
        F[(long)e*1536 + col] = f2bf(v);
        partial += v * kb[col];
    }
    const float tot = blockReduceSum(partial, red, t);
    if (t == 0) bvec[ge] = tot;
}

// ---------------------------------------------------------------------------
// row softmax, bf16 P written IN-PLACE into the first half of the row's own
// f32 storage (own-row aliasing, barrier-separated). P layout: lda=512 ushorts.
// ---------------------------------------------------------------------------
__launch_bounds__(256)
__global__ void softmax_ip_k(float* __restrict__ S)
{
    const long row = blockIdx.x;
    const int t = threadIdx.x;
    __shared__ float red[256];
    const float v = S[row*256 + t];
    red[t] = v; __syncthreads();
#pragma unroll
    for (int s = 128; s > 0; s >>= 1) { if (t < s) red[t] = fmaxf(red[t], red[t+s]); __syncthreads(); }
    const float mx = red[0]; __syncthreads();
    const float e = __expf(v - mx);
    red[t] = e; __syncthreads();
#pragma unroll
    for (int s = 128; s > 0; s >>= 1) { if (t < s) red[t] += red[t+s]; __syncthreads(); }
    const float sum = red[0];
    ((ushortT*)S)[row*512 + t] = f2bf(e / sum);
}

// ---------------- fused LayerNorm + head dot (unchanged — validated) --------
__launch_bounds__(256)
__global__ void ln_head_k(int b0, const ushortT* __restrict__ F, const void* __restrict__ lng,
                          const void* __restrict__ lnb, const void* __restrict__ hW,
                          const void* __restrict__ hB, float* __restrict__ gout,
                          const int* __restrict__ flagp)
{
    const int fl = *flagp;
    const int e = blockIdx.x, t = threadIdx.x;
    __shared__ float red[256];
    float xv[6];
    float s = 0.f;
#pragma unroll
    for (int c = 0; c < 6; ++c) { xv[c] = bf2f(F[(long)e*1536 + c*256 + t]); s += xv[c]; }
    const float tot = blockReduceSum(s, red, t);
    const float mu = tot * (1.f/1536.f);
    float ss = 0.f;
#pragma unroll
    for (int c = 0; c < 6; ++c) { const float d = xv[c] - mu; ss += d*d; }
    const float tot2 = blockReduceSum(ss, red, t);
    const float rs = rsqrtf(tot2 * (1.f/1536.f) + EPSC);
    float p = 0.f;
#pragma unroll
    for (int c = 0; c < 6; ++c) {
        const int col = c*256 + t;
        p += (get1(lng, col, fl) * (xv[c] - mu) * rs + get1(lnb, col, fl)) * get1(hW, col, fl);
    }
    const float tot3 = blockReduceSum(p, red, t);
    if (t == 0) gout[b0*256 + e] = tot3 + get1(hB, 0, fl);
}

// ---------------- final output assembly (unchanged — validated) -------------
__launch_bounds__(128)
__global__ void final_k(const float* __restrict__ gout, const int* __restrict__ se,
                        const int* __restrict__ te, const int* __restrict__ sorted_orig,
                        const void* __restrict__ ea, float* __restrict__ out,
                        const int* __restrict__ flagp)
{
    const int fl = *flagp;
    const int b = blockIdx.x, j = threadIdx.x;
    const int e0 = b*256 + 2*j, e1 = e0 + 1;
    const float p0 = gout[e0], p1 = gout[e1];
    const int idx = (p1 < p0) ? 1 : 0;
    const float val = idx ? p1 : p0;
    const int eo = idx ? e1 : e0;
    const int orig = clampi(sorted_orig[eo], 0, EDIR-1);
    const float cls = get1(ea, 2L*orig + 1, fl);
    out[(b*128 + j)*2 + 0] = (float)se[e0];
    out[(b*128 + j)*2 + 1] = (float)te[e0];
    out[32768 + b*128 + j] = val;
    out[32768 + 16384 + b*128 + j] = cls;
}

// ---------------------------------------------------------------------------
// Launch. R9: revert big GEMMs to the validated 128^2 bgemm_k (R8's 256^2
// counted-vmcnt regressed, 709 vs 843 TF). gconv2's two generic gemms fused
// into ONE fast bgemm: h = relu([ag|h1] @ Wg2T^T + b), K=512, via combined
// ah_c buffer (same bytes as old h1_c+ag_c) + phase-W Wg2T/g2bf prep.
// ---------------------------------------------------------------------------
extern "C" void kernel_launch(void* const* d_in, const int* in_sizes, int n_in,
                              void* d_out, int out_size, void* d_ws, size_t ws_size,
                              hipStream_t stream)
{
    (void)out_size;

    const void* x     = d_in[0];
    const int*  edges = (const int*)d_in[1];
    const void* ea    = d_in[2];

    int ws0 = 3;
    while (ws0 < n_in && in_sizes[ws0] != 3) ++ws0;
    if (ws0 + 27 > n_in) ws0 = 5;

    const void* wembW  = d_in[ws0 + 0];
    const void* wembB  = d_in[ws0 + 1];
    const void* g1Wrel = d_in[ws0 + 2];
    const void* g1brel = d_in[ws0 + 3];
    const void* g1Wroot= d_in[ws0 + 4];
    const void* g2Wrel = d_in[ws0 + 5];
    const void* g2brel = d_in[ws0 + 6];
    const void* g2Wroot= d_in[ws0 + 7];
    const void* gnw    = d_in[ws0 + 8];
    const void* gnb    = d_in[ws0 + 9];
    const void* gnms   = d_in[ws0 + 10];
    const void* eembW  = d_in[ws0 + 11];
    const void* eembB  = d_in[ws0 + 12];
    const void* qkvW   = d_in[ws0 + 13];
    const void* qkvb   = d_in[ws0 + 14];
    const void* inWq   = d_in[ws0 + 15];
    const void* inWk   = d_in[ws0 + 16];
    const void* inWv   = d_in[ws0 + 17];
    const void* inbq   = d_in[ws0 + 18];
    // inbk (ws0+19): row-constant score terms -> drop in softmax
    const void* inbv   = d_in[ws0 + 20];
    const void* outW   = d_in[ws0 + 21];
    const void* outb   = d_in[ws0 + 22];
    const void* lng    = d_in[ws0 + 23];
    const void* lnb    = d_in[ws0 + 24];
    const void* headW  = d_in[ws0 + 25];
    const void* headb  = d_in[ws0 + 26];

    char* ws = (char*)d_ws;
    size_t off = 0;
    auto alloc = [&](size_t bytes) {
        void* p = ws + off;
        off = (off + bytes + 255) & ~(size_t)255;
        return p;
    };
    // ---- fixed region (~12 MB) ----
    int*     dflag  = (int*)    alloc(256);
    float*   gout   = (float*)  alloc(EKEEP*4);
    int*     sorted = (int*)    alloc(EKEEP*4);
    int*     seg    = (int*)    alloc(EKEEP*4);
    int*     teg    = (int*)    alloc(EKEEP*4);
    float*   bvec   = (float*)  alloc(EKEEP*4);
    float*   bqc    = (float*)  alloc(1536*4);
    float*   bvc    = (float*)  alloc(1536*4);
    float*   kb     = (float*)  alloc(1536*4);
    float*   bvo    = (float*)  alloc(1536*4);
    float*   g2bf   = (float*)  alloc(512*4);
    float*   colpart= (float*)  alloc(64L*1536*4);
    ushortT* Wg2T   = (ushortT*)alloc(512L*512*2);     // fused gconv2 B, [n][k]
    ushortT* MpWv   = (ushortT*)alloc(2L*1536*1536*2); // [Mp^T ; Wvo] contiguous
    ushortT* MpT    = MpWv;                            // Mp^T, [n][k]
    ushortT* Wvo    = MpWv + 1536L*1536;               // Wvo, ROW-major [m][k]
    const size_t fixedB = off;

    // ---- union region (phase-W scratch; overlaps chunk scratch) ----
    // layout: [Wqc][Wkc][Wvc][outWT][qkvWbf(3)][inWqT][inWkT][inWvT]
    const long W2 = 1536L * 1536;
    ushortT* Wqc    = (ushortT*)(ws + fixedB);
    ushortT* Wkc    = Wqc + W2;
    ushortT* Wvc    = Wqc + 2*W2;
    ushortT* outWT  = Wqc + 3*W2;
    ushortT* qkvWbf = Wqc + 4*W2;     // 1536x4608
    ushortT* inWqT  = Wqc + 7*W2;
    ushortT* inWkT  = Wqc + 8*W2;     // adjacent (z=3 B stride = W2)
    ushortT* inWvT  = Wqc + 9*W2;

    // ---- chunk scratch (G=128 guaranteed: perG = 1.97 MB -> 263 MB total) --
    const size_t perG = 64L*512*2 + 64L*512*2 + 2L*256*1536*2 + 256L*256*4;
    int G = 128;
    while (G > 2 && fixedB + (size_t)G*perG + 65536 > ws_size) G >>= 1;

    size_t coff = fixedB;
    auto calloc2 = [&](size_t bytes) {
        void* p = ws + coff;
        coff = (coff + bytes + 255) & ~(size_t)255;
        return p;
    };
    ushortT* h_c  = (ushortT*)calloc2((size_t)G*64*512*2);
    ushortT* ah_c = (ushortT*)calloc2((size_t)G*64*512*2);   // [ag | h1] K=512
    ushortT* F_c  = (ushortT*)calloc2((size_t)G*256*1536*2);
    ushortT* T_c  = (ushortT*)calloc2((size_t)G*256*1536*2); // T, then V'^T
    float*   S_c  = (float*)  calloc2((size_t)G*256*256*4);

    const float scale = 0.02551551815399144f;  // 1/sqrt(1536)
    const dim3 blk(256);

    detect_k<<<1, blk, 0, stream>>>((const unsigned int*)x, dflag);
    sort_k<<<128, blk, 0, stream>>>(edges, sorted, seg, teg);

    // ---- phase W ----
    convbf_k<<<(1536*4608/4 + 255)/256, blk, 0, stream>>>(qkvW, qkvWbf, 1536L*4608/4, dflag);
    tconvbf_k<<<dim3(48,48), blk, 0, stream>>>(inWq, inWqT, dflag);
    tconvbf_k<<<dim3(48,48), blk, 0, stream>>>(inWk, inWkT, dflag);
    tconvbf_k<<<dim3(48,48), blk, 0, stream>>>(inWv, inWvT, dflag);
    tconvbf_k<<<dim3(48,48), blk, 0, stream>>>(outW, outWT, dflag);
    tconv512_k<<<dim3(16,8), blk, 0, stream>>>(g2Wrel, Wg2T, 0, dflag);
    tconv512_k<<<dim3(16,8), blk, 0, stream>>>(g2Wroot, Wg2T, 256, dflag);
    convf32_k<<<2, blk, 0, stream>>>(g2brel, g2bf, 512, dflag);
    // (Wqc,Wkc,Wvc) z=3 batch: A = qkvWbf k-slices (sA=1536), B = inW{q,k,v}T
    bgemm_k<ushortT,false,false,false><<<dim3(12,12,3), blk, 0, stream>>>(
        qkvWbf, inWqT, nullptr, Wqc, 1536, 4608, 1536, 1536,
        1536L, W2, W2, 0, 0, 1.f);
    colcomb_part_k<<<dim3(6,64), blk, 0, stream>>>(qkvb, C_RT, 0, inWq, C_RT, colpart, dflag);
    colcomb_red_k<<<6, blk, 0, stream>>>(colpart, inbq, C_RT, bqc, dflag);
    // kb = scale * Wkc @ bqc
    rowdot_k<<<1536, blk, 0, stream>>>(Wkc, bqc, kb, scale);
    colcomb_part_k<<<dim3(6,64), blk, 0, stream>>>(qkvb, C_RT, 3072, inWv, C_RT, colpart, dflag);
    colcomb_red_k<<<6, blk, 0, stream>>>(colpart, inbv, C_RT, bvc, dflag);
    // (MpT, Wvo) z=2 batch, unscaled (scale lives in the S-gemm alpha):
    //   z=0: MpT = Wkc @ Wqc^T
    //   z=1: Wvo = Wvc @ outWT^T = Wvc @ outW   (row-major Wvo)
    bgemm_k<ushortT,false,false,false><<<dim3(12,12,2), blk, 0, stream>>>(
        Wkc, Wqc, nullptr, MpT, 1536, 1536, 1536, 1536,
        W2, 3*W2, W2, 0, 0, 1.f);
    colcomb_part_k<<<dim3(6,64), blk, 0, stream>>>(bvc, C_F32, 0, outW, C_RT, colpart, dflag);
    colcomb_red_k<<<6, blk, 0, stream>>>(colpart, outb, C_RT, bvo, dflag);

    // ---- per-chunk pipeline ----
    const int nchunk = 128 / G;
    const int EC = G * 256;
    for (int c = 0; c < nchunk; ++c) {
        const int b0 = c * G;
        const int maxn = G*64 - 1;
        gconv1_k<<<G, blk, 0, stream>>>(b0, x, edges, ea, wembW, wembB,
                                        g1Wrel, g1brel, g1Wroot, ah_c, dflag);
        gconv2_agg_k<<<G, blk, 0, stream>>>(b0, ah_c, edges, ea, wembW, wembB, dflag);
        // h = relu([ag|h1] @ Wg2T^T + g2b)   (fused gconv2, K=512)
        bgemm_k<ushortT,true,false,true><<<dim3(4, G/2, 1), blk, 0, stream>>>(
            ah_c, Wg2T, g2bf, h_c, 512, 512, 512, 512, 0,0,0, 0, 0, 1.f);
        gnorm_k<<<dim3(G,2), blk, 0, stream>>>(h_c, gnw, gnb, gnms, dflag);
        fbuild_k<<<EC, blk, 0, stream>>>(b0, maxn, h_c, sorted, seg, teg, ea,
                                         eembW, eembB, kb, F_c, bvec, dflag);
        // T = F @ Mp^T
        bgemm_k<ushortT,false,false,false><<<dim3(12, EC/128, 1), blk, 0, stream>>>(
            F_c, MpT, nullptr, T_c, 1536, 1536, 1536, 1536, 0,0,0, 0,0, 1.f);
        // S = scale * T@F^T + bvec
        bgemm_k<float,true,false,false><<<dim3(2, 2, G), blk, 0, stream>>>(
            T_c, F_c, bvec + (long)b0*256, S_c, 1536, 1536, 1536, 256,
            256L*1536, 256L*1536, 65536L, 0, 256, scale);
        softmax_ip_k<<<EC, blk, 0, stream>>>(S_c);
        // V'^T_b = Wvo @ F_b^T   (into T_c; T dead after S-gemm)
        bgemm_k<ushortT,false,false,false><<<dim3(2, 12, G), blk, 0, stream>>>(
            Wvo, F_c, nullptr, T_c, 1536, 1536, 1536, 256,
            0L, 256L*1536, 256L*1536, 0, 0, 1.f);
        // F_b += P_b @ V'_b + bvo   (A = bf16 P in S_c, lda=512 ushorts)
        bgemm_k<ushortT,true,true,false><<<dim3(12, 2, G), blk, 0, stream>>>(
            (const ushortT*)S_c, T_c, bvo, F_c, 256, 512, 256, 1536,
            131072L, 256L*1536, 256L*1536, 0, 0, 1.f);
        ln_head_k<<<EC, blk, 0, stream>>>(b0, F_c, lng, lnb, headW, headb, gout, dflag);
    }

    final_k<<<128, dim3(128), 0, stream>>>(gout, seg, teg, sorted, ea, (float*)d_out, dflag);
}